// Round 1
// baseline (6041.487 us; speedup 1.0000x reference)
//
#include <hip/hip_runtime.h>
#include <math.h>

#define N_NODES 10000
#define N_EDGES 320000

// ---------------- setup kernels ----------------

__global__ void k_init(float* deg, int* cnt, int* fill, int n) {
    int i = blockIdx.x * blockDim.x + threadIdx.x;
    if (i < n) { deg[i] = 0.f; cnt[i] = 0; fill[i] = 0; }
}

__global__ void k_deg(const int* __restrict__ ei, const float* __restrict__ w,
                      float* deg, int E) {
    int e = blockIdx.x * blockDim.x + threadIdx.x;
    if (e < E) atomicAdd(&deg[ei[e]], w[e]);
}

__global__ void k_dis(float* deg, int n) {
    int i = blockIdx.x * blockDim.x + threadIdx.x;
    if (i < n) {
        float d = deg[i];
        deg[i] = (d > 0.f) ? (float)(1.0 / sqrt((double)d)) : 0.f;
    }
}

__global__ void k_norm(const int* __restrict__ ei, const float* __restrict__ w,
                       const float* __restrict__ dis, float* __restrict__ normw,
                       int* cnt, int E) {
    int e = blockIdx.x * blockDim.x + threadIdx.x;
    if (e < E) {
        int s = ei[e], d = ei[E + e];
        normw[e] = -dis[s] * w[e] * dis[d];
        atomicAdd(&cnt[d], 1);
    }
}

// single-block exclusive scan over 10000 counts -> rowptr[0..n]
__global__ void k_scan(const int* __restrict__ cnt, int* __restrict__ rowptr, int n) {
    __shared__ int part[1024];
    const int PER = 10;  // 1024*10 = 10240 >= n
    int t = threadIdx.x;
    int base = t * PER;
    int local[PER];
    int s = 0;
    for (int j = 0; j < PER; j++) {
        int idx = base + j;
        int v = (idx < n) ? cnt[idx] : 0;
        local[j] = v; s += v;
    }
    part[t] = s;
    __syncthreads();
    for (int off = 1; off < 1024; off <<= 1) {
        int v = part[t];
        int u = (t >= off) ? part[t - off] : 0;
        __syncthreads();
        part[t] = v + u;
        __syncthreads();
    }
    int excl = (t > 0) ? part[t - 1] : 0;
    for (int j = 0; j < PER; j++) {
        int idx = base + j;
        if (idx < n) rowptr[idx] = excl;
        excl += local[j];
    }
    if (t == 1023) rowptr[n] = part[1023];
}

__global__ void k_fill(const int* __restrict__ ei, const float* __restrict__ normw,
                       const int* __restrict__ rowptr, int* fill,
                       int* __restrict__ csr_src, float* __restrict__ csr_norm, int E) {
    int e = blockIdx.x * blockDim.x + threadIdx.x;
    if (e < E) {
        int d = ei[E + e];
        int pos = atomicAdd(&fill[d], 1);
        int idx = rowptr[d] + pos;
        csr_src[idx] = ei[e];
        csr_norm[idx] = normw[e];
    }
}

// ---------------- fused Chebyshev step ----------------
// mode 0: t2 = t1 (copy h), acc = bias + t2 @ Wk
// mode 1: t2 = propagate(t1), acc += t2 @ Wk
// mode 2: t2 = 2*propagate(t1) - t0, acc += t2 @ Wk
// lastact: 0 none (store acc), 1 silu -> outp, 2 sigmoid -> outp
// One wave (64 lanes) per node. lane = (e_off, c): c = lane % C_PAD.
// t buffers and acc always have row stride 64 floats; t1 uses t1_stride.

template <int C_IN, int C_PAD, int EPT, int C_OUT>
__global__ __launch_bounds__(256) void k_step(
    const int* __restrict__ rowptr, const int* __restrict__ csr_src,
    const float* __restrict__ csr_norm,
    const float* __restrict__ t0, const float* __restrict__ t1, int t1_stride,
    float* __restrict__ t2, float* __restrict__ acc,
    const float* __restrict__ Wk, const float* __restrict__ bias,
    float* __restrict__ outp, int out_stride,
    int mode, int lastact)
{
    static_assert((C_PAD & (C_PAD - 1)) == 0, "C_PAD must be pow2");
    constexpr int CSH = (C_PAD == 64) ? 6 : (C_PAD == 32) ? 5 : (C_PAD == 16) ? 4
                        : (C_PAD == 8) ? 3 : (C_PAD == 4) ? 2 : 0;
    __shared__ float lds[4][C_PAD];

    int tid = threadIdx.x;
    int w = tid >> 6;
    int lane = tid & 63;
    int node = blockIdx.x * 4 + w;   // grid is exactly N/4 blocks
    int c = lane & (C_PAD - 1);
    int e_off = lane >> CSH;

    float t2v = 0.f;
    if (mode == 0) {
        if (e_off == 0 && c < C_IN) t2v = t1[node * t1_stride + c];
    } else {
        float agg = 0.f;
        int rb = rowptr[node], re = rowptr[node + 1];
        for (int e = rb + e_off; e < re; e += EPT) {
            int s = csr_src[e];
            float nw = csr_norm[e];
            if (c < C_IN) agg += nw * t1[s * t1_stride + c];
        }
#pragma unroll
        for (int off = 32; off >= C_PAD; off >>= 1) agg += __shfl_xor(agg, off);
        if (mode == 1) t2v = agg;
        else           t2v = 2.f * agg - t0[node * 64 + c];
    }

    if (e_off == 0 && c < C_IN) {
        t2[node * 64 + c] = t2v;
        lds[w][c] = t2v;
    }
    __syncthreads();

    int o = lane;
    if (o < C_OUT) {
        float a;
        if (mode == 0) a = bias ? bias[o] : 0.f;
        else           a = acc[node * 64 + o];
#pragma unroll
        for (int cc = 0; cc < C_IN; cc++) a += lds[w][cc] * Wk[cc * C_OUT + o];
        if (lastact == 0) {
            acc[node * 64 + o] = a;
        } else {
            float r = (lastact == 1) ? a / (1.f + expf(-a))   // silu
                                     : 1.f / (1.f + expf(-a)); // sigmoid
            outp[node * out_stride + o] = r;
        }
    }
}

// ---------------- host ----------------

extern "C" void kernel_launch(void* const* d_in, const int* in_sizes, int n_in,
                              void* d_out, int out_size, void* d_ws, size_t ws_size,
                              hipStream_t stream) {
    const float* x  = (const float*)d_in[0];
    const int*   ei = (const int*)d_in[1];
    const float* ew = (const float*)d_in[2];
    const float* W1 = (const float*)d_in[3];
    const float* b1 = (const float*)d_in[4];
    const float* W2 = (const float*)d_in[5];
    const float* b2 = (const float*)d_in[6];
    const float* W3 = (const float*)d_in[7];
    const float* b3 = (const float*)d_in[8];
    const float* W4 = (const float*)d_in[9];
    float* out = (float*)d_out;

    const int n = N_NODES, E = N_EDGES;

    char* ws = (char*)d_ws;
    size_t off = 0;
    auto alloc = [&](size_t bytes) -> void* {
        void* p = ws + off;
        off += (bytes + 255) & ~(size_t)255;
        return p;
    };
    float* deg      = (float*)alloc(n * 4);          // becomes dis in-place
    int*   cnt      = (int*)alloc(n * 4);
    int*   fill     = (int*)alloc(n * 4);
    int*   rowptr   = (int*)alloc((n + 4) * 4);
    float* normw    = (float*)alloc(E * 4);
    int*   csr_src  = (int*)alloc(E * 4);
    float* csr_norm = (float*)alloc(E * 4);
    float* tA   = (float*)alloc(n * 64 * 4);
    float* tB   = (float*)alloc(n * 64 * 4);
    float* tC   = (float*)alloc(n * 64 * 4);
    float* accb = (float*)alloc(n * 64 * 4);
    float* h1   = (float*)alloc(n * 64 * 4);
    float* h2   = (float*)alloc(n * 64 * 4);
    float* h3   = (float*)alloc(n * 64 * 4);
    (void)ws_size; (void)n_in; (void)in_sizes; (void)out_size;

    // ---- graph preprocessing: degree, norm, dst-CSR ----
    k_init<<<(n + 255) / 256, 256, 0, stream>>>(deg, cnt, fill, n);
    k_deg <<<(E + 255) / 256, 256, 0, stream>>>(ei, ew, deg, E);
    k_dis <<<(n + 255) / 256, 256, 0, stream>>>(deg, n);
    k_norm<<<(E + 255) / 256, 256, 0, stream>>>(ei, ew, deg, normw, cnt, E);
    k_scan<<<1, 1024, 0, stream>>>(cnt, rowptr, n);
    k_fill<<<(E + 255) / 256, 256, 0, stream>>>(ei, normw, rowptr, fill,
                                                csr_src, csr_norm, E);

    const int grid = n / 4;  // 2500, exact
    float* t[3] = {tA, tB, tC};

    // ---- Layer 1: ChebConv K=120, 4 -> 64, silu ----
    {
        const int K = 120, CI = 4, CO = 64;
        k_step<4, 4, 16, 64><<<grid, 256, 0, stream>>>(
            rowptr, csr_src, csr_norm, nullptr, x, CI, t[0], accb,
            W1, b1, h1, 64, 0, 0);
        k_step<4, 4, 16, 64><<<grid, 256, 0, stream>>>(
            rowptr, csr_src, csr_norm, nullptr, x, CI, t[1], accb,
            W1 + 1 * CI * CO, nullptr, h1, 64, 1, 0);
        for (int k = 2; k < K; k++) {
            k_step<4, 4, 16, 64><<<grid, 256, 0, stream>>>(
                rowptr, csr_src, csr_norm, t[(k - 2) % 3], t[(k - 1) % 3], 64,
                t[k % 3], accb, W1 + k * CI * CO, nullptr, h1, 64, 2,
                (k == K - 1) ? 1 : 0);
        }
    }

    // ---- Layer 2: ChebConv K=120, 64 -> 60, silu ----
    {
        const int K = 120, CI = 64, CO = 60;
        k_step<64, 64, 1, 60><<<grid, 256, 0, stream>>>(
            rowptr, csr_src, csr_norm, nullptr, h1, 64, t[0], accb,
            W2, b2, h2, 64, 0, 0);
        k_step<64, 64, 1, 60><<<grid, 256, 0, stream>>>(
            rowptr, csr_src, csr_norm, nullptr, h1, 64, t[1], accb,
            W2 + 1 * CI * CO, nullptr, h2, 64, 1, 0);
        for (int k = 2; k < K; k++) {
            k_step<64, 64, 1, 60><<<grid, 256, 0, stream>>>(
                rowptr, csr_src, csr_norm, t[(k - 2) % 3], t[(k - 1) % 3], 64,
                t[k % 3], accb, W2 + k * CI * CO, nullptr, h2, 64, 2,
                (k == K - 1) ? 1 : 0);
        }
    }

    // ---- Layer 3: ChebConv K=20, 60 -> 30, silu ----
    {
        const int K = 20, CI = 60, CO = 30;
        k_step<60, 64, 1, 30><<<grid, 256, 0, stream>>>(
            rowptr, csr_src, csr_norm, nullptr, h2, 64, t[0], accb,
            W3, b3, h3, 64, 0, 0);
        k_step<60, 64, 1, 30><<<grid, 256, 0, stream>>>(
            rowptr, csr_src, csr_norm, nullptr, h2, 64, t[1], accb,
            W3 + 1 * CI * CO, nullptr, h3, 64, 1, 0);
        for (int k = 2; k < K; k++) {
            k_step<60, 64, 1, 30><<<grid, 256, 0, stream>>>(
                rowptr, csr_src, csr_norm, t[(k - 2) % 3], t[(k - 1) % 3], 64,
                t[k % 3], accb, W3 + k * CI * CO, nullptr, h3, 64, 2,
                (k == K - 1) ? 1 : 0);
        }
    }

    // ---- Layer 4: ChebConv K=1, 30 -> 1, sigmoid -> d_out ----
    k_step<30, 32, 2, 1><<<grid, 256, 0, stream>>>(
        rowptr, csr_src, csr_norm, nullptr, h3, 64, t[0], accb,
        W4, nullptr, out, 1, 0, 2);
}